// Round 1
// baseline (239.359 us; speedup 1.0000x reference)
//
#include <hip/hip_runtime.h>
#include <hip/hip_bf16.h>
#include <math.h>

typedef short bf16x8 __attribute__((ext_vector_type(8)));
typedef float f32x4 __attribute__((ext_vector_type(4)));

#define MFMA16x16(a, b, c) __builtin_amdgcn_mfma_f32_16x16x32_bf16(a, b, c, 0, 0, 0)

__device__ __forceinline__ float silu_f(float v) { return v / (1.0f + __expf(-v)); }
// XOR swizzle for [row][128B] LDS tiles: kills the 16/32-way bank conflict on ds_read_b128
__device__ __forceinline__ int swz128(int b) { return b ^ (((b >> 7) & 7) << 4); }

__device__ __forceinline__ unsigned short f2bf(float f) {  // RNE f32->bf16
  union { float f; unsigned u; } x; x.f = f;
  unsigned r = x.u + 0x7fffu + ((x.u >> 16) & 1u);
  return (unsigned short)(r >> 16);
}
__device__ __forceinline__ float bf2f(unsigned short h) {
  union { unsigned u; float f; } x; x.u = ((unsigned)h) << 16;
  return x.f;
}

__device__ __forceinline__ void gload_lds16(const void* g, void* l) {
  __builtin_amdgcn_global_load_lds((__attribute__((address_space(1))) unsigned int*)g,
                                   (__attribute__((address_space(3))) unsigned int*)l,
                                   16, 0, 0);
}

// ---------- offsets prep: tolerate int64 or int32 storage ----------
__global__ void k_prep_offs(const int* __restrict__ raw, int* __restrict__ offs, int Bp1) {
  int t = threadIdx.x;
  // int64 little-endian: raw[3] is high word of offsets[1] == 0. int32: raw[3]=offsets[3]>0.
  bool is64 = (raw[3] == 0);
  if (t < Bp1) offs[t] = is64 ? raw[2 * t] : raw[t];
}

// ---------- uvqk (512x2048 f32) -> uvqkT (2048x512 bf16), transposed ----------
__global__ __launch_bounds__(256) void k_conv_uvqkT(const float* __restrict__ uvqk,
                                                    unsigned short* __restrict__ uvqkT) {
  __shared__ float tile[32][33];
  int n0 = blockIdx.x * 32, k0 = blockIdx.y * 32;
  int tx = threadIdx.x & 31;
  int ty = threadIdx.x >> 5;  // 0..7
#pragma unroll
  for (int i = 0; i < 4; ++i)
    tile[ty + 8 * i][tx] = uvqk[(size_t)(k0 + ty + 8 * i) * 2048 + n0 + tx];
  __syncthreads();
#pragma unroll
  for (int i = 0; i < 4; ++i) {
    int nn = ty + 8 * i;
    uvqkT[(size_t)(n0 + nn) * 512 + k0 + tx] = f2bf(tile[tx][nn]);
  }
}

__global__ __launch_bounds__(256) void k_conv_bf16(const float* __restrict__ in,
                                                   unsigned short* __restrict__ out, int n) {
  int i = blockIdx.x * 256 + threadIdx.x;
  if (i < n) out[i] = f2bf(in[i]);
}

// ---------- LayerNorm(x) -> bf16, one wave per 512-row ----------
__global__ __launch_bounds__(256) void k_ln_x(const float* __restrict__ x,
                                              unsigned short* __restrict__ normed, int T) {
  int lane = threadIdx.x & 63, wid = threadIdx.x >> 6;
  int row = blockIdx.x * 4 + wid;
  if (row >= T) return;
  const float4* xr = (const float4*)(x + (size_t)row * 512);
  float4 a = xr[lane * 2], b = xr[lane * 2 + 1];
  float s = a.x + a.y + a.z + a.w + b.x + b.y + b.z + b.w;
  float s2 = a.x * a.x + a.y * a.y + a.z * a.z + a.w * a.w +
             b.x * b.x + b.y * b.y + b.z * b.z + b.w * b.w;
#pragma unroll
  for (int m = 1; m < 64; m <<= 1) { s += __shfl_xor(s, m); s2 += __shfl_xor(s2, m); }
  float mean = s * (1.0f / 512.0f);
  float var = s2 * (1.0f / 512.0f) - mean * mean;
  float rstd = rsqrtf(var + 1e-6f);
  float v[8] = {a.x, a.y, a.z, a.w, b.x, b.y, b.z, b.w};
  unsigned short o[8];
#pragma unroll
  for (int j = 0; j < 8; ++j) o[j] = f2bf((v[j] - mean) * rstd);
  *(uint4*)(normed + (size_t)row * 512 + lane * 8) = *(uint4*)o;
}

// ---------- o_input = u * LayerNorm(attn) -> bf16 ----------
__global__ __launch_bounds__(256) void k_ln_mul_u(const float* __restrict__ attn,
                                                  const unsigned short* __restrict__ mm,
                                                  unsigned short* __restrict__ oin, int T) {
  int lane = threadIdx.x & 63, wid = threadIdx.x >> 6;
  int row = blockIdx.x * 4 + wid;
  if (row >= T) return;
  const float4* xr = (const float4*)(attn + (size_t)row * 512);
  float4 a = xr[lane * 2], b = xr[lane * 2 + 1];
  float s = a.x + a.y + a.z + a.w + b.x + b.y + b.z + b.w;
  float s2 = a.x * a.x + a.y * a.y + a.z * a.z + a.w * a.w +
             b.x * b.x + b.y * b.y + b.z * b.z + b.w * b.w;
#pragma unroll
  for (int m = 1; m < 64; m <<= 1) { s += __shfl_xor(s, m); s2 += __shfl_xor(s2, m); }
  float mean = s * (1.0f / 512.0f);
  float var = s2 * (1.0f / 512.0f) - mean * mean;
  float rstd = rsqrtf(var + 1e-6f);
  uint4 ub = *(const uint4*)(mm + (size_t)row * 2048 + lane * 8);  // u = mm[:, 0:512]
  const unsigned short* us = (const unsigned short*)&ub;
  float v[8] = {a.x, a.y, a.z, a.w, b.x, b.y, b.z, b.w};
  unsigned short o[8];
#pragma unroll
  for (int j = 0; j < 8; ++j) o[j] = f2bf((v[j] - mean) * rstd * bf2f(us[j]));
  *(uint4*)(oin + (size_t)row * 512 + lane * 8) = *(uint4*)o;
}

// ---------- MFMA GEMM, 128x128 tile, BK=64, Bt is (N,K) row-major ----------
// MODE 0: C = silu(A@Bt^T) -> bf16 ; MODE 1: C = A@Bt^T + bias + xres -> f32
template <int MODE>
__global__ __launch_bounds__(256) void k_gemm_bt(const unsigned short* __restrict__ A,
                                                 const unsigned short* __restrict__ Bt,
                                                 void* __restrict__ Cout,
                                                 const float* __restrict__ bias,
                                                 const float* __restrict__ xres,
                                                 int M, int Nn, int K, int ntn) {
  __shared__ __align__(16) char lds[32768];
  char* ldsA = lds;
  char* ldsB = lds + 16384;
  int bid = blockIdx.x;
  int mt = bid / ntn, nt = bid - mt * ntn;
  int m0 = mt * 128, n0 = nt * 128;
  int tid = threadIdx.x, lane = tid & 63, wid = tid >> 6;
  int wm = wid >> 1, wn = wid & 1;
  int fr = lane & 15, fq = lane >> 4;
  f32x4 acc[4][4] = {};
  int nK = K >> 6;
  int lco = (lane & 7) * 16;  // byte-in-row (pre-swizzle)
  int lrow8 = lane >> 3;      // row within 1KB chunk
  for (int kt = 0; kt < nK; ++kt) {
    int k0 = kt << 6;
#pragma unroll
    for (int p = 0; p < 4; ++p) {
      int chunk = wid * 4 + p;
      int row = chunk * 8 + lrow8;
      int colb = lco ^ ((row & 7) << 4);  // pre-swizzled global source -> linear LDS dest
      int ar = m0 + row; if (ar >= M) ar = M - 1;
      gload_lds16((const char*)(A + (size_t)ar * K + k0) + colb, ldsA + chunk * 1024);
      gload_lds16((const char*)(Bt + (size_t)(n0 + row) * K + k0) + colb, ldsB + chunk * 1024);
    }
    __syncthreads();
    bf16x8 af[4][2], bfr[4][2];
#pragma unroll
    for (int mi = 0; mi < 4; ++mi) {
      int r = wm * 64 + mi * 16 + fr;
#pragma unroll
      for (int kk = 0; kk < 2; ++kk)
        af[mi][kk] = *(const bf16x8*)(ldsA + swz128(r * 128 + kk * 64 + fq * 16));
    }
#pragma unroll
    for (int ni = 0; ni < 4; ++ni) {
      int r = wn * 64 + ni * 16 + fr;
#pragma unroll
      for (int kk = 0; kk < 2; ++kk)
        bfr[ni][kk] = *(const bf16x8*)(ldsB + swz128(r * 128 + kk * 64 + fq * 16));
    }
#pragma unroll
    for (int mi = 0; mi < 4; ++mi)
#pragma unroll
      for (int ni = 0; ni < 4; ++ni) {
        acc[mi][ni] = MFMA16x16(af[mi][0], bfr[ni][0], acc[mi][ni]);
        acc[mi][ni] = MFMA16x16(af[mi][1], bfr[ni][1], acc[mi][ni]);
      }
    __syncthreads();
  }
#pragma unroll
  for (int mi = 0; mi < 4; ++mi) {
#pragma unroll
    for (int j = 0; j < 4; ++j) {
      int r = m0 + wm * 64 + mi * 16 + fq * 4 + j;
      if (r >= M) continue;
#pragma unroll
      for (int ni = 0; ni < 4; ++ni) {
        int c = n0 + wn * 64 + ni * 16 + fr;
        float v = acc[mi][ni][j];
        if (MODE == 0) {
          ((unsigned short*)Cout)[(size_t)r * Nn + c] = f2bf(silu_f(v));
        } else {
          ((float*)Cout)[(size_t)r * Nn + c] = v + bias[c] + xres[(size_t)r * 512 + c];
        }
      }
    }
  }
}

// ---------- jagged causal SiLU-attention ----------
// mm row layout: [u 0..511 | v 512..1023 | q 1024..1535 | k 1536..2047], head-major 64 each
__global__ __launch_bounds__(256) void k_attn(const unsigned short* __restrict__ mm,
                                              const int* __restrict__ offs,
                                              float* __restrict__ attn, float inv_n) {
  int b = blockIdx.y >> 3, h = blockIdx.y & 7;
  int off = offs[b];
  int len = offs[b + 1] - off;
  int q0 = blockIdx.x * 64;
  if (q0 >= len) return;
  int tid = threadIdx.x, lane = tid & 63, wid = tid >> 6;
  int fr = lane & 15, fq = lane >> 4;
  __shared__ __align__(16) char sK[8192];   // [s=64][d=64] bf16, swizzled
  __shared__ __align__(16) char sVT[8192];  // [d=64][s=64] bf16, swizzled (transposed V)
  __shared__ __align__(16) char sP[8192];   // per-wave [16][64] bf16, swizzled
  const unsigned short* qp = mm + (size_t)off * 2048 + 1024 + h * 64;
  const unsigned short* kp = mm + (size_t)off * 2048 + 1536 + h * 64;
  const unsigned short* vp = mm + (size_t)off * 2048 + 512 + h * 64;
  int qrow = q0 + wid * 16 + fr;
  int qrc = qrow < len ? qrow : len - 1;
  bf16x8 aq[2];
  aq[0] = *(const bf16x8*)(qp + (size_t)qrc * 2048 + fq * 8);
  aq[1] = *(const bf16x8*)(qp + (size_t)qrc * 2048 + 32 + fq * 8);
  f32x4 accO[4] = {};
  int nkt = (q0 >> 6) + 1;
  char* pw = sP + wid * 2048;
  for (int kt = 0; kt < nkt; ++kt) {
    int s0 = kt << 6;
    __syncthreads();
#pragma unroll 2
    for (int i = tid; i < 512; i += 256) {  // K tile: 64 rows x 128B
      int row = i >> 3, cb = (i & 7) << 4;
      uint4 val = {0u, 0u, 0u, 0u};
      if (s0 + row < len) val = *(const uint4*)((const char*)(kp + (size_t)(s0 + row) * 2048) + cb);
      *(uint4*)(sK + swz128(row * 128 + cb)) = val;
    }
#pragma unroll 2
    for (int i = tid; i < 512; i += 256) {  // V tile, transposed into sVT
      int s = i >> 3, d0 = (i & 7) << 3;
      uint4 val = {0u, 0u, 0u, 0u};
      if (s0 + s < len) val = *(const uint4*)((const char*)(vp + (size_t)(s0 + s) * 2048) + d0 * 2);
      const unsigned short* e = (const unsigned short*)&val;
#pragma unroll
      for (int j = 0; j < 8; ++j)
        *(unsigned short*)(sVT + swz128((d0 + j) * 128 + s * 2)) = e[j];
    }
    __syncthreads();
    // S = Q K^T for this wave's 16 q-rows; silu/n + causal mask; P -> wave-private LDS
#pragma unroll
    for (int ni = 0; ni < 4; ++ni) {
      f32x4 sa = {};
      bf16x8 b0 = *(const bf16x8*)(sK + swz128((ni * 16 + fr) * 128 + fq * 16));
      bf16x8 b1 = *(const bf16x8*)(sK + swz128((ni * 16 + fr) * 128 + 64 + fq * 16));
      sa = MFMA16x16(aq[0], b0, sa);
      sa = MFMA16x16(aq[1], b1, sa);
#pragma unroll
      for (int j = 0; j < 4; ++j) {
        int pq = q0 + wid * 16 + fq * 4 + j;
        int ps = s0 + ni * 16 + fr;
        float v = (ps <= pq) ? silu_f(sa[j]) * inv_n : 0.0f;
        *(unsigned short*)(pw + swz128((fq * 4 + j) * 128 + (ni * 16 + fr) * 2)) = f2bf(v);
      }
    }
    // O += P V (A-frags from wave-private P; compiler orders same-wave LDS RAW)
    bf16x8 pa0 = *(const bf16x8*)(pw + swz128(fr * 128 + fq * 16));
    bf16x8 pa1 = *(const bf16x8*)(pw + swz128(fr * 128 + 64 + fq * 16));
#pragma unroll
    for (int ni = 0; ni < 4; ++ni) {
      bf16x8 v0 = *(const bf16x8*)(sVT + swz128((ni * 16 + fr) * 128 + fq * 16));
      bf16x8 v1 = *(const bf16x8*)(sVT + swz128((ni * 16 + fr) * 128 + 64 + fq * 16));
      accO[ni] = MFMA16x16(pa0, v0, accO[ni]);
      accO[ni] = MFMA16x16(pa1, v1, accO[ni]);
    }
  }
#pragma unroll
  for (int ni = 0; ni < 4; ++ni)
#pragma unroll
    for (int j = 0; j < 4; ++j) {
      int pq = q0 + wid * 16 + fq * 4 + j;
      if (pq < len)
        attn[(size_t)(off + pq) * 512 + h * 64 + ni * 16 + fr] = accO[ni][j];
    }
}

extern "C" void kernel_launch(void* const* d_in, const int* in_sizes, int n_in,
                              void* d_out, int out_size, void* d_ws, size_t ws_size,
                              hipStream_t stream) {
  const float* x = (const float*)d_in[0];
  const int* xoff = (const int*)d_in[1];
  // d_in[2] = invalid_attn_mask (causal tril) -- applied analytically
  const float* uvqk = (const float*)d_in[3];
  const float* ow = (const float*)d_in[4];
  const float* obias = (const float*)d_in[5];

  const int D = 512;
  int T = in_sizes[0] / D;
  int B = in_sizes[1] - 1;
  int nm = 1;
  while ((long long)nm * nm < (long long)in_sizes[2]) nm <<= 1;  // mask dim (1024)

  char* w = (char*)d_ws;
  size_t p = 0;
  auto alloc = [&](size_t bytes) { size_t r = p; p += (bytes + 255) & ~(size_t)255; return r; };
  int* offs = (int*)(w + alloc(sizeof(int) * (size_t)(B + 1)));
  unsigned short* normed = (unsigned short*)(w + alloc((size_t)T * 512 * 2));
  unsigned short* mm = (unsigned short*)(w + alloc((size_t)T * 2048 * 2));
  float* attn = (float*)(w + alloc((size_t)T * 512 * 4));
  unsigned short* oin = (unsigned short*)(w + alloc((size_t)T * 512 * 2));
  unsigned short* uvqkT = (unsigned short*)(w + alloc((size_t)2048 * 512 * 2));
  unsigned short* owb = (unsigned short*)(w + alloc((size_t)512 * 512 * 2));

  k_prep_offs<<<1, 32, 0, stream>>>(xoff, offs, B + 1);
  k_conv_uvqkT<<<dim3(64, 16), 256, 0, stream>>>(uvqk, uvqkT);
  k_conv_bf16<<<1024, 256, 0, stream>>>(ow, owb, 512 * 512);
  k_ln_x<<<(T + 3) / 4, 256, 0, stream>>>(x, normed, T);
  int ntm = (T + 127) / 128;
  k_gemm_bt<0><<<ntm * 16, 256, 0, stream>>>(normed, uvqkT, (void*)mm, nullptr, nullptr,
                                             T, 2048, 512, 16);
  k_attn<<<dim3(nm / 64, B * 8), 256, 0, stream>>>(mm, offs, attn, 1.0f / (float)nm);
  k_ln_mul_u<<<(T + 3) / 4, 256, 0, stream>>>(attn, mm, oin, T);
  k_gemm_bt<1><<<ntm * 4, 256, 0, stream>>>(oin, owb, d_out, obias, x, T, 512, 512, 4);
}